// Round 2
// baseline (214.293 us; speedup 1.0000x reference)
//
#include <hip/hip_runtime.h>
#include <math.h>

// Chamfer loss, two 16384x3 fp32 clouds. Pure fp32 VALU problem (no fp32 MFMA
// on CDNA4; K=3 makes MFMA pointless anyway). Inner loop is 4 VALU ops/pair:
// track m = min_j(||b_j||^2 - 2 a.b_j), add ||a||^2 once at the end.
//
// Pass 1: per-query partial min over one of S DB slices -> d_ws.
//         S=16 => 2048 blocks = 8 blocks/CU = 32 waves/CU (occupancy fix).
// Pass 2: single block fuses slice-combine + sqrt + full reduction -> scalar.

#define TILE 1024   // DB points per LDS tile: 1024 * 16B = 16 KB

__global__ __launch_bounds__(256) void chamfer_partial_min(
    const float* __restrict__ state_x, const float* __restrict__ target,
    float* __restrict__ mins, int N, int S)
{
    const int tid = threadIdx.x;
    const int block_q = blockIdx.x / S;     // which 256-query chunk
    const int s = blockIdx.x % S;           // which DB slice
    const int qi = block_q * 256 + tid;     // global query id in [0, 2N)

    const float* qcloud;
    const float* db;
    int qidx;
    if (qi < N) { qcloud = target;  db = state_x; qidx = qi;     }  // dist1
    else        { qcloud = state_x; db = target;  qidx = qi - N; }  // dist2

    const float qx = qcloud[3 * qidx + 0];
    const float qy = qcloud[3 * qidx + 1];
    const float qz = qcloud[3 * qidx + 2];
    const float m2x = -2.0f * qx, m2y = -2.0f * qy, m2z = -2.0f * qz;

    __shared__ float4 tile[TILE];

    const int sliceN = N / S;
    const int base0 = s * sliceN;
    // 4 independent min chains: v_min dep latency (~4cy) never critical.
    float m0 = 3.0e38f, m1 = 3.0e38f, m2 = 3.0e38f, m3 = 3.0e38f;

    for (int t0 = 0; t0 < sliceN; t0 += TILE) {
        // Stage tile: (bx, by, bz, ||b||^2) per point.
        for (int p = tid; p < TILE; p += 256) {
            const int g = base0 + t0 + p;
            const float bx = db[3 * g + 0];
            const float by = db[3 * g + 1];
            const float bz = db[3 * g + 2];
            tile[p] = make_float4(bx, by, bz, bx * bx + by * by + bz * bz);
        }
        __syncthreads();

        // 4 VALU ops per DB point; LDS reads are broadcast (conflict-free).
        #pragma unroll 2
        for (int j = 0; j < TILE; j += 4) {
            const float4 b0 = tile[j + 0];
            const float4 b1 = tile[j + 1];
            const float4 b2 = tile[j + 2];
            const float4 b3 = tile[j + 3];
            m0 = fminf(m0, fmaf(b0.z, m2z, fmaf(b0.y, m2y, fmaf(b0.x, m2x, b0.w))));
            m1 = fminf(m1, fmaf(b1.z, m2z, fmaf(b1.y, m2y, fmaf(b1.x, m2x, b1.w))));
            m2 = fminf(m2, fmaf(b2.z, m2z, fmaf(b2.y, m2y, fmaf(b2.x, m2x, b2.w))));
            m3 = fminf(m3, fmaf(b3.z, m2z, fmaf(b3.y, m2y, fmaf(b3.x, m2x, b3.w))));
        }
        __syncthreads();
    }

    mins[(size_t)s * (size_t)(2 * N) + qi] = fminf(fminf(m0, m1), fminf(m2, m3));
}

// Single block: combine S slice-mins, add ||a||^2, sqrt, reduce to scalar.
__global__ __launch_bounds__(1024) void chamfer_finish(
    const float* __restrict__ state_x, const float* __restrict__ target,
    const float* __restrict__ mins, float* __restrict__ out, int N, int S)
{
    const int tid = threadIdx.x;
    const int twoN = 2 * N;

    float acc = 0.0f;
    for (int qi = tid; qi < twoN; qi += 1024) {
        const float* qcloud = (qi < N) ? target : state_x;
        const int qidx = (qi < N) ? qi : qi - N;
        const float qx = qcloud[3 * qidx + 0];
        const float qy = qcloud[3 * qidx + 1];
        const float qz = qcloud[3 * qidx + 2];
        const float a2 = qx * qx + qy * qy + qz * qz;

        float m = 3.0e38f;
        for (int s = 0; s < S; ++s)
            m = fminf(m, mins[(size_t)s * (size_t)twoN + qi]);

        acc += sqrtf(fmaxf(a2 + m, 0.0f));
    }

    // wave64 shuffle reduce, then cross-wave via LDS (16 waves).
    for (int off = 32; off > 0; off >>= 1) acc += __shfl_down(acc, off, 64);
    __shared__ float wsum[16];
    if ((tid & 63) == 0) wsum[tid >> 6] = acc;
    __syncthreads();
    if (tid < 64) {
        float v = (tid < 16) ? wsum[tid] : 0.0f;
        for (int off = 8; off > 0; off >>= 1) v += __shfl_down(v, off, 64);
        if (tid == 0)
            out[0] = v * 5.0f / (float)N;   // (mean1+mean2)*0.5*10
    }
}

extern "C" void kernel_launch(void* const* d_in, const int* in_sizes, int n_in,
                              void* d_out, int out_size, void* d_ws, size_t ws_size,
                              hipStream_t stream)
{
    const float* state_x = (const float*)d_in[0];
    const float* target  = (const float*)d_in[1];
    float* out = (float*)d_out;

    const int N = in_sizes[0] / 3;          // 16384
    const int nQBlocks = (2 * N) / 256;     // 128

    // S DB-slices; mins needs S*2N floats in ws. Prefer 16 for occupancy
    // (2048 blocks = 8 blocks/CU = 32 waves/CU).
    int S = 16;
    while (S > 1 && (size_t)S * (size_t)(2 * N) * sizeof(float) > ws_size)
        S >>= 1;

    float* mins = (float*)d_ws;

    chamfer_partial_min<<<nQBlocks * S, 256, 0, stream>>>(state_x, target, mins, N, S);
    chamfer_finish<<<1, 1024, 0, stream>>>(state_x, target, mins, out, N, S);
}

// Round 3
// 119.547 us; speedup vs baseline: 1.7925x; 1.7925x over previous
//
#include <hip/hip_runtime.h>
#include <math.h>

// Chamfer loss, two 16384x3 fp32 clouds. Pure fp32 VALU problem.
// Inner form: m = min_j(||b_j||^2 - 2 a.b_j); add ||a||^2 at the end.
//
// R3 design:
//  - Q=8 queries per thread: one broadcast ds_read_b128 per DB point feeds
//    8x(3 FMA + min) = 32 VALU ops, so the DS pipe (~6cy/instr even for
//    broadcast) drops well below the VALU pipe. (R1/R2 had 1 LDS : 4 VALU,
//    which made LDS co-dominant -> 76us instead of the 27us VALU floor.)
//  - S DB-slices (prefer 128) -> 16 qchunks x S = up to 2048 blocks
//    = 8 blocks/CU = 32 waves/CU.
//  - Pass 2 is WIDE (128 blocks) + one atomicAdd per block; no single-block
//    tail (R2's 98us mistake).

#define TILE 1024   // DB points per LDS tile: 16 KB
#define QPT 8       // queries per thread

__global__ __launch_bounds__(256) void chamfer_partial_min(
    const float* __restrict__ state_x, const float* __restrict__ target,
    float* __restrict__ mins, int N, int S)
{
    const int tid = threadIdx.x;
    const int qchunk = blockIdx.x / S;      // which 2048-query chunk (uniform)
    const int s = blockIdx.x % S;           // which DB slice (uniform)
    const int qbase = qchunk * (256 * QPT); // chunk start in [0, 2N)

    // 2048-query chunks never straddle the N boundary (2048 | 16384),
    // so the direction is block-uniform.
    const float* qcloud;
    const float* db;
    int qoff;
    if (qbase < N) { qcloud = target;  db = state_x; qoff = qbase;     }
    else           { qcloud = state_x; db = target;  qoff = qbase - N; }

    // Load this thread's 8 queries (strided by 256 for coalescing).
    float m2x[QPT], m2y[QPT], m2z[QPT], m[QPT];
    #pragma unroll
    for (int q = 0; q < QPT; ++q) {
        const int qidx = qoff + q * 256 + tid;
        m2x[q] = -2.0f * qcloud[3 * qidx + 0];
        m2y[q] = -2.0f * qcloud[3 * qidx + 1];
        m2z[q] = -2.0f * qcloud[3 * qidx + 2];
        m[q] = 3.0e38f;
    }

    __shared__ float4 tile[TILE];

    const int sliceN = N / S;
    const int base0 = s * sliceN;

    for (int t0 = 0; t0 < sliceN; t0 += TILE) {
        const int cnt = (sliceN - t0 < TILE) ? (sliceN - t0) : TILE;
        for (int p = tid; p < cnt; p += 256) {
            const int g = base0 + t0 + p;
            const float bx = db[3 * g + 0];
            const float by = db[3 * g + 1];
            const float bz = db[3 * g + 2];
            tile[p] = make_float4(bx, by, bz, bx * bx + by * by + bz * bz);
        }
        __syncthreads();

        // 2 points x 8 queries per iteration: 2 LDS b128 : 64 VALU.
        for (int j = 0; j < cnt; j += 2) {
            const float4 b0 = tile[j + 0];
            const float4 b1 = tile[j + 1];
            #pragma unroll
            for (int q = 0; q < QPT; ++q) {
                const float d0 = fmaf(b0.z, m2z[q], fmaf(b0.y, m2y[q], fmaf(b0.x, m2x[q], b0.w)));
                const float d1 = fmaf(b1.z, m2z[q], fmaf(b1.y, m2y[q], fmaf(b1.x, m2x[q], b1.w)));
                m[q] = fminf(m[q], fminf(d0, d1));
            }
        }
        __syncthreads();
    }

    const int twoN = 2 * N;
    #pragma unroll
    for (int q = 0; q < QPT; ++q) {
        const int qi = qbase + q * 256 + tid;
        mins[(size_t)s * (size_t)twoN + qi] = m[q];
    }
}

// Wide finish: 128 blocks. Combine S slice-mins, add ||a||^2, sqrt,
// block-reduce, one atomicAdd per block.
__global__ __launch_bounds__(256) void chamfer_finish(
    const float* __restrict__ state_x, const float* __restrict__ target,
    const float* __restrict__ mins, float* __restrict__ out, int N, int S)
{
    const int tid = threadIdx.x;
    const int qi = blockIdx.x * 256 + tid;
    const int twoN = 2 * N;

    const float* qcloud = (qi < N) ? target : state_x;
    const int qidx = (qi < N) ? qi : qi - N;
    const float qx = qcloud[3 * qidx + 0];
    const float qy = qcloud[3 * qidx + 1];
    const float qz = qcloud[3 * qidx + 2];
    const float a2 = qx * qx + qy * qy + qz * qz;

    float m = 3.0e38f;
    for (int s = 0; s < S; ++s)
        m = fminf(m, mins[(size_t)s * (size_t)twoN + qi]);

    float v = sqrtf(fmaxf(a2 + m, 0.0f));

    for (int off = 32; off > 0; off >>= 1) v += __shfl_down(v, off, 64);
    __shared__ float wsum[4];
    if ((tid & 63) == 0) wsum[tid >> 6] = v;
    __syncthreads();
    if (tid == 0) {
        const float bsum = wsum[0] + wsum[1] + wsum[2] + wsum[3];
        atomicAdd(out, bsum * 5.0f / (float)N);  // (mean1+mean2)*0.5*10
    }
}

extern "C" void kernel_launch(void* const* d_in, const int* in_sizes, int n_in,
                              void* d_out, int out_size, void* d_ws, size_t ws_size,
                              hipStream_t stream)
{
    const float* state_x = (const float*)d_in[0];
    const float* target  = (const float*)d_in[1];
    float* out = (float*)d_out;

    const int N = in_sizes[0] / 3;          // 16384
    const int nQChunks = (2 * N) / (256 * QPT);  // 16

    // S DB-slices; mins needs S*2N floats in ws. Prefer 128
    // (16*128 = 2048 blocks = 8 blocks/CU).
    int S = 128;
    while (S > 4 && (size_t)S * (size_t)(2 * N) * sizeof(float) > ws_size)
        S >>= 1;

    float* mins = (float*)d_ws;

    hipMemsetAsync(d_out, 0, sizeof(float), stream);
    chamfer_partial_min<<<nQChunks * S, 256, 0, stream>>>(state_x, target, mins, N, S);
    chamfer_finish<<<(2 * N) / 256, 256, 0, stream>>>(state_x, target, mins, out, N, S);
}

// Round 4
// 102.375 us; speedup vs baseline: 2.0932x; 1.1677x over previous
//
#include <hip/hip_runtime.h>
#include <math.h>

// Chamfer loss, two 16384x3 fp32 clouds.
// R4: (a) packed fp32 math: v_pk_fma_f32 does 2 FMA/lane/instr (CDNA4's
//     157.3TF path). 2 DB points per v2f -> 3 pk_fma + 1 v_min3 per 2 pairs
//     = 2 VALU instr/pair (R3 was 4). Floor ~13.7us.
//     (b) replace the S x 2N mins matrix (16.8MB HBM round-trip, R3's 75us
//     tail) with a single 2N-entry encoded-uint atomicMin array (128KB).

typedef float v2f __attribute__((ext_vector_type(2)));

#define QPT 16          // queries per thread
#define TILE_PAIRS 64   // 128 DB points per LDS tile (2 float4 per pair)

// Monotone float->uint map: a<b  <=>  enc(a)<enc(b).
__device__ __forceinline__ unsigned enc_f32(float f) {
    int b = __float_as_int(f);
    return (b >= 0) ? ((unsigned)b | 0x80000000u) : ~(unsigned)b;
}
__device__ __forceinline__ float dec_f32(unsigned k) {
    int b = (k & 0x80000000u) ? (int)(k & 0x7FFFFFFFu) : ~(int)k;
    return __int_as_float(b);
}

__global__ __launch_bounds__(256) void chamfer_partial_min(
    const float* __restrict__ state_x, const float* __restrict__ target,
    unsigned* __restrict__ mins_u, int N, int S)
{
    const int tid = threadIdx.x;
    const int qchunk = blockIdx.x / S;          // uniform per block
    const int s = blockIdx.x % S;
    const int qbase = qchunk * (256 * QPT);     // in [0, 2N), chunk=4096 | N

    const float* qcloud;
    const float* db;
    int qoff;
    if (qbase < N) { qcloud = target;  db = state_x; qoff = qbase;     }
    else           { qcloud = state_x; db = target;  qoff = qbase - N; }

    // Per-thread queries: -2*coord splatted into v2f for pk_fma.
    v2f mx[QPT], my[QPT], mz[QPT];
    float m[QPT];
    #pragma unroll
    for (int q = 0; q < QPT; ++q) {
        const int qidx = qoff + q * 256 + tid;
        const float x = -2.0f * qcloud[3 * qidx + 0];
        const float y = -2.0f * qcloud[3 * qidx + 1];
        const float z = -2.0f * qcloud[3 * qidx + 2];
        mx[q] = (v2f){x, x};
        my[q] = (v2f){y, y};
        mz[q] = (v2f){z, z};
        m[q] = 3.0e38f;
    }

    // LDS: per point-pair two float4: {x0,x1,y0,y1} and {z0,z1,w0,w1}.
    __shared__ float4 tile[TILE_PAIRS * 2];

    const int sliceN = N / S;                   // multiple of 2*TILE_PAIRS
    const int base0 = s * sliceN;

    for (int t0 = 0; t0 < sliceN; t0 += 2 * TILE_PAIRS) {
        if (tid < TILE_PAIRS) {
            const int g0 = base0 + t0 + 2 * tid;
            const float x0 = db[3 * g0 + 0], y0 = db[3 * g0 + 1], z0 = db[3 * g0 + 2];
            const float x1 = db[3 * g0 + 3], y1 = db[3 * g0 + 4], z1 = db[3 * g0 + 5];
            tile[2 * tid + 0] = make_float4(x0, x1, y0, y1);
            tile[2 * tid + 1] = make_float4(z0, z1,
                                            fmaf(x0, x0, fmaf(y0, y0, z0 * z0)),
                                            fmaf(x1, x1, fmaf(y1, y1, z1 * z1)));
        }
        __syncthreads();

        #pragma unroll 2
        for (int p = 0; p < TILE_PAIRS; ++p) {
            const float4 A = tile[2 * p + 0];   // x0 x1 y0 y1  (broadcast b128)
            const float4 B = tile[2 * p + 1];   // z0 z1 w0 w1
            const v2f X = (v2f){A.x, A.y};
            const v2f Y = (v2f){A.z, A.w};
            const v2f Z = (v2f){B.x, B.y};
            const v2f W = (v2f){B.z, B.w};
            #pragma unroll
            for (int q = 0; q < QPT; ++q) {
                v2f d = __builtin_elementwise_fma(X, mx[q], W);
                d = __builtin_elementwise_fma(Y, my[q], d);
                d = __builtin_elementwise_fma(Z, mz[q], d);
                m[q] = fminf(fminf(m[q], d.x), d.y);   // v_min3_f32
            }
        }
        __syncthreads();
    }

    #pragma unroll
    for (int q = 0; q < QPT; ++q) {
        const int qi = qbase + q * 256 + tid;
        atomicMin(&mins_u[qi], enc_f32(m[q]));
    }
}

// Wide finish: 128 blocks; decode min, add ||a||^2, sqrt, block-reduce,
// one atomicAdd per block.
__global__ __launch_bounds__(256) void chamfer_finish(
    const float* __restrict__ state_x, const float* __restrict__ target,
    const unsigned* __restrict__ mins_u, float* __restrict__ out, int N)
{
    const int tid = threadIdx.x;
    const int qi = blockIdx.x * 256 + tid;

    const float* qcloud = (qi < N) ? target : state_x;
    const int qidx = (qi < N) ? qi : qi - N;
    const float qx = qcloud[3 * qidx + 0];
    const float qy = qcloud[3 * qidx + 1];
    const float qz = qcloud[3 * qidx + 2];
    const float a2 = qx * qx + qy * qy + qz * qz;

    const float mm = dec_f32(mins_u[qi]);
    float v = sqrtf(fmaxf(a2 + mm, 0.0f));

    for (int off = 32; off > 0; off >>= 1) v += __shfl_down(v, off, 64);
    __shared__ float wsum[4];
    if ((tid & 63) == 0) wsum[tid >> 6] = v;
    __syncthreads();
    if (tid == 0) {
        const float bsum = wsum[0] + wsum[1] + wsum[2] + wsum[3];
        atomicAdd(out, bsum * 5.0f / (float)N);  // (mean1+mean2)*0.5*10
    }
}

extern "C" void kernel_launch(void* const* d_in, const int* in_sizes, int n_in,
                              void* d_out, int out_size, void* d_ws, size_t ws_size,
                              hipStream_t stream)
{
    const float* state_x = (const float*)d_in[0];
    const float* target  = (const float*)d_in[1];
    float* out = (float*)d_out;

    const int N = in_sizes[0] / 3;               // 16384
    const int twoN = 2 * N;
    const int nQChunks = twoN / (256 * QPT);     // 8

    // S slices of the DB; sliceN = N/S must be a multiple of 128.
    // S=128 -> grid 1024 = 4 blocks/CU.
    int S = 128;
    while (S > 1 && (N / S) % (2 * TILE_PAIRS) != 0) S >>= 1;

    unsigned* mins_u = (unsigned*)d_ws;          // 2N u32 = 256 KB

    hipMemsetAsync(mins_u, 0xFF, (size_t)twoN * sizeof(unsigned), stream);
    hipMemsetAsync(d_out, 0, sizeof(float), stream);
    chamfer_partial_min<<<nQChunks * S, 256, 0, stream>>>(state_x, target, mins_u, N, S);
    chamfer_finish<<<twoN / 256, 256, 0, stream>>>(state_x, target, mins_u, out, N);
}